// Round 21
// baseline (872.373 us; speedup 1.0000x reference)
//
#include <hip/hip_runtime.h>

#define NN 200000
#define EE 6400000L
#define NCB 196          // coarse buckets of 1024 nodes
#define CAP 36864        // fixed bucket capacity; mean 32653 + 6σ + pad < CAP
#define TILE 4096        // LDS 22.7KB -> 7 blocks/CU for passA
#define NTILE 1563       // ceil(6400000/4096)

typedef unsigned u32x4 __attribute__((ext_vector_type(4)));
typedef float    f32x4 __attribute__((ext_vector_type(4)));

__device__ inline void f4add(float4& a, const float4 v) {
    a.x += v.x; a.y += v.y; a.z += v.z; a.w += v.w;
}

// NT load of 4 csr entries (ext_vector_type is legal for the builtin)
__device__ inline u32x4 nt_load4(const unsigned* p) {
    return __builtin_nontemporal_load((const u32x4*)p);
}

// ---------------------------------------------------------------------------
// Edge-index dtype hedge (int64 vs int32): if int64 with values < 2^31, every
// odd 32-bit word is zero. flag=1 -> int64 (word idx = elem<<1), 0 -> int32.
// Also initializes the per-bucket segment cursors gcur[b] = b*CAP.
// ---------------------------------------------------------------------------
__global__ void k_detect(const int* __restrict__ w, int* __restrict__ flag,
                         int* __restrict__ gcur) {
    __shared__ int any;
    if (threadIdx.x == 0) any = 0;
    __syncthreads();
    int found = 0;
    for (int i = threadIdx.x; i < 8192; i += 256)
        if (w[2 * i + 1] != 0) found = 1;
    if (found) atomicOr(&any, 1);
    if (threadIdx.x < NCB) gcur[threadIdx.x] = threadIdx.x * CAP;
    __syncthreads();
    if (threadIdx.x == 0) flag[0] = any ? 0 : 1;
}

// Partition into coarse buckets with tile-exclusive segments (fixed capacity).
// stage entry: src[17:0] | local_dst[27:18]. Streaming traffic is NT.
__global__ __launch_bounds__(256) void k_passA(
    const int* __restrict__ ew, const int* __restrict__ flag,
    int* __restrict__ gcur, unsigned* __restrict__ stage, long e) {
    __shared__ unsigned lv[TILE];
    __shared__ unsigned char lb[TILE];
    __shared__ int lh[NCB], lseg[NCB], lcur[NCB];
    for (int i = threadIdx.x; i < NCB; i += 256) { lh[i] = 0; lcur[i] = 0; }
    __syncthreads();
    long t0 = (long)blockIdx.x * TILE;
    int cnt = (int)min((long)TILE, e - t0);
    int shift = *flag;
    for (int i = threadIdx.x; i < cnt; i += 256) {
        int s = __builtin_nontemporal_load(ew + ((t0 + i) << shift));
        int d = __builtin_nontemporal_load(ew + ((EE + t0 + i) << shift));
        int b = d >> 10;
        lv[i] = (unsigned)s | ((unsigned)(d & 1023) << 18);
        lb[i] = (unsigned char)b;
        atomicAdd(&lh[b], 1);
    }
    __syncthreads();
    for (int i = threadIdx.x; i < NCB; i += 256)
        if (lh[i]) lseg[i] = atomicAdd(&gcur[i], lh[i]);
    __syncthreads();
    for (int i = threadIdx.x; i < cnt; i += 256) {
        int b = lb[i];
        int r = atomicAdd(&lcur[b], 1);
        __builtin_nontemporal_store(lv[i], stage + lseg[b] + r);
    }
}

// Per-bucket counting sort: stage (bucket-grouped) -> csr (node-grouped, src).
// Node segments padded to 4-entry (16B) alignment for uint4 csr loads.
// Emits odn = {offset, degree} and dis. Streaming traffic is NT.
__global__ __launch_bounds__(1024) void k_sortB(
    const unsigned* __restrict__ stage, const int* __restrict__ gcur,
    float* __restrict__ dis, int2* __restrict__ odn,
    unsigned* __restrict__ csr, int n) {
    __shared__ int cnt[1024];
    __shared__ int cur[1024];
    __shared__ int wsum[16];
    int t = threadIdx.x, B = blockIdx.x;
    cnt[t] = 0;
    __syncthreads();
    int s0 = B * CAP, s1 = gcur[B];
    for (int i = s0 + t; i < s1; i += 1024)
        atomicAdd(&cnt[__builtin_nontemporal_load(stage + i) >> 18], 1);
    __syncthreads();
    int c = cnt[t];
    int pc = (c + 3) & ~3;              // pad to 4 entries (16B) for uint4 loads
    int lane = t & 63, w = t >> 6;
    int s = pc;
#pragma unroll
    for (int o = 1; o < 64; o <<= 1) {
        int u = __shfl_up(s, o, 64);
        if (lane >= o) s += u;
    }
    if (lane == 63) wsum[w] = s;
    __syncthreads();
    int add = 0;
    for (int k = 0; k < w; ++k) add += wsum[k];
    int excl = s - pc + add;
    cur[t] = excl;
    int node = B * 1024 + t;
    if (node < n) {
        odn[node] = make_int2(s0 + excl, c);
        dis[node] = rsqrtf((float)(c + 1));
    }
    __syncthreads();
    for (int i = s0 + t; i < s1; i += 1024) {
        unsigned v = __builtin_nontemporal_load(stage + i);
        int pos = s0 + atomicAdd(&cur[v >> 18], 1);
        __builtin_nontemporal_store(v & 0x3FFFF, csr + pos);
    }
}

// Layer 1 matmul: hws = dis ⊙ (x @ W1), row-major float4 quads. x reads NT.
__global__ __launch_bounds__(256) void k_mm1(
    const float* __restrict__ x, const float* __restrict__ W,
    const float* __restrict__ dis, float4* __restrict__ outr, int n) {
    __shared__ float Wl[256 * 16];
    int t = threadIdx.x;
#pragma unroll
    for (int i = 0; i < 4; ++i)
        ((float4*)Wl)[t + i * 256] = ((const float4*)W)[t + i * 256];
    __syncthreads();

    int node = blockIdx.x * 256 + t;
    if (node >= n) return;

    const f32x4* xr = (const f32x4*)(x + (long)node * 256);
    float acc[16];
#pragma unroll
    for (int o = 0; o < 16; ++o) acc[o] = 0.f;

#pragma unroll 8
    for (int kk = 0; kk < 64; ++kk) {
        f32x4 xv = __builtin_nontemporal_load(xr + kk);
#pragma unroll
        for (int q = 0; q < 4; ++q) {
            float xs = xv[q];
            const float4* wr = (const float4*)&Wl[(kk * 4 + q) * 16];
#pragma unroll
            for (int oo = 0; oo < 4; ++oo) {
                float4 wv = wr[oo];
                acc[oo * 4 + 0] = fmaf(xs, wv.x, acc[oo * 4 + 0]);
                acc[oo * 4 + 1] = fmaf(xs, wv.y, acc[oo * 4 + 1]);
                acc[oo * 4 + 2] = fmaf(xs, wv.z, acc[oo * 4 + 2]);
                acc[oo * 4 + 3] = fmaf(xs, wv.w, acc[oo * 4 + 3]);
            }
        }
    }
    float dv = dis[node];
#pragma unroll
    for (int q = 0; q < 4; ++q)
        outr[node * 4 + q] = make_float4(acc[q * 4] * dv, acc[q * 4 + 1] * dv,
                                         acc[q * 4 + 2] * dv, acc[q * 4 + 3] * dv);
}

// Shared gather core: quad-chunk unroll — 4 lane-uniform uint4 csr loads (NT:
// csr is a read-once stream; keep it out of L2 so the random tab rows stay
// resident) and 16 independent 16B gathers (temporal) in flight per lane.
__device__ inline float4 gather_quad(const unsigned* __restrict__ csr, int s0,
                                     int dg, const float4* __restrict__ tab,
                                     int j) {
    float4 a0 = make_float4(0.f, 0.f, 0.f, 0.f);
    float4 a1 = make_float4(0.f, 0.f, 0.f, 0.f);
    float4 a2 = make_float4(0.f, 0.f, 0.f, 0.f);
    float4 a3 = make_float4(0.f, 0.f, 0.f, 0.f);
    int k = 0;
    for (; k + 16 <= dg; k += 16) {
        u32x4 e0 = nt_load4(csr + s0 + k);
        u32x4 e1 = nt_load4(csr + s0 + k + 4);
        u32x4 e2 = nt_load4(csr + s0 + k + 8);
        u32x4 e3 = nt_load4(csr + s0 + k + 12);
        f4add(a0, tab[e0.x * 4 + j]); f4add(a1, tab[e1.x * 4 + j]);
        f4add(a2, tab[e2.x * 4 + j]); f4add(a3, tab[e3.x * 4 + j]);
        f4add(a0, tab[e0.y * 4 + j]); f4add(a1, tab[e1.y * 4 + j]);
        f4add(a2, tab[e2.y * 4 + j]); f4add(a3, tab[e3.y * 4 + j]);
        f4add(a0, tab[e0.z * 4 + j]); f4add(a1, tab[e1.z * 4 + j]);
        f4add(a2, tab[e2.z * 4 + j]); f4add(a3, tab[e3.z * 4 + j]);
        f4add(a0, tab[e0.w * 4 + j]); f4add(a1, tab[e1.w * 4 + j]);
        f4add(a2, tab[e2.w * 4 + j]); f4add(a3, tab[e3.w * 4 + j]);
    }
    if (k + 8 <= dg) {
        u32x4 eL = nt_load4(csr + s0 + k);
        u32x4 eH = nt_load4(csr + s0 + k + 4);
        f4add(a0, tab[eL.x * 4 + j]); f4add(a1, tab[eH.x * 4 + j]);
        f4add(a0, tab[eL.y * 4 + j]); f4add(a1, tab[eH.y * 4 + j]);
        f4add(a0, tab[eL.z * 4 + j]); f4add(a1, tab[eH.z * 4 + j]);
        f4add(a0, tab[eL.w * 4 + j]); f4add(a1, tab[eH.w * 4 + j]);
        k += 8;
    }
    if (k + 4 <= dg) {
        u32x4 e = nt_load4(csr + s0 + k);
        f4add(a0, tab[e.x * 4 + j]);
        f4add(a1, tab[e.y * 4 + j]);
        f4add(a2, tab[e.z * 4 + j]);
        f4add(a3, tab[e.w * 4 + j]);
        k += 4;
    }
    for (; k < dg; ++k)
        f4add(a0, tab[__builtin_nontemporal_load(csr + s0 + k) * 4 + j]);
    f4add(a0, a1); f4add(a2, a3); f4add(a0, a2);
    return a0;
}

// Layer-1 gather + relu + FUSED mm2 + scale. 4 lanes/node, 64 nodes/block
// (grid exactly n/64 -> barrier-safe). Epilogue: h1 quad -> LDS (stride 17),
// barrier, each lane computes quad j of dis*(h1@W2). Output store NT.
__global__ __launch_bounds__(256) void k_g16a(
    const int2* __restrict__ odn, const unsigned* __restrict__ csr,
    const float* __restrict__ dis, const float4* __restrict__ tab,
    const float* __restrict__ b1v, const float* __restrict__ W2,
    float4* __restrict__ out2) {
    __shared__ float h1s[64 * 17];
    __shared__ float W2l[256];
    int t = threadIdx.x;
    if (t < 64) ((float4*)W2l)[t] = ((const float4*)W2)[t];
    int node = blockIdx.x * 64 + (t >> 2);
    int j = t & 3;
    int2 od = odn[node];
    float4 aA = gather_quad(csr, od.x, od.y, tab, j);
    f4add(aA, tab[node * 4 + j]);               // self-loop (pre-scaled)
    float dv = dis[node];
    float4 bb = ((const float4*)b1v)[j];
    float4 r = make_float4(fmaf(dv, aA.x, bb.x), fmaf(dv, aA.y, bb.y),
                           fmaf(dv, aA.z, bb.z), fmaf(dv, aA.w, bb.w));
    r.x = fmaxf(r.x, 0.f); r.y = fmaxf(r.y, 0.f);
    r.z = fmaxf(r.z, 0.f); r.w = fmaxf(r.w, 0.f);
    int nl = t >> 2;
    h1s[nl * 17 + 4 * j + 0] = r.x;
    h1s[nl * 17 + 4 * j + 1] = r.y;
    h1s[nl * 17 + 4 * j + 2] = r.z;
    h1s[nl * 17 + 4 * j + 3] = r.w;
    __syncthreads();
    // mm2: quad j of dis * (h1 @ W2)
    float4 acc = make_float4(0.f, 0.f, 0.f, 0.f);
#pragma unroll
    for (int kk = 0; kk < 16; ++kk) {
        float hv = h1s[nl * 17 + kk];
        float4 wv = ((const float4*)&W2l[kk * 16])[j];
        acc.x = fmaf(hv, wv.x, acc.x);
        acc.y = fmaf(hv, wv.y, acc.y);
        acc.z = fmaf(hv, wv.z, acc.z);
        acc.w = fmaf(hv, wv.w, acc.w);
    }
    f32x4 ov = {acc.x * dv, acc.y * dv, acc.z * dv, acc.w * dv};
    __builtin_nontemporal_store(ov, (f32x4*)(out2 + (long)node * 4 + j));
}

// Layer-2 gather + relu + FUSED mm3 + scale: writes hws3 (1 float/node).
__global__ __launch_bounds__(256) void k_g16b(
    const int2* __restrict__ odn, const unsigned* __restrict__ csr,
    const float* __restrict__ dis, const float4* __restrict__ tab,
    const float* __restrict__ b2v, const float* __restrict__ W3,
    float* __restrict__ hws3) {
    int t = threadIdx.x;
    int node = blockIdx.x * 64 + (t >> 2);
    int j = t & 3;
    int2 od = odn[node];
    float4 aA = gather_quad(csr, od.x, od.y, tab, j);
    f4add(aA, tab[node * 4 + j]);               // self-loop (pre-scaled)
    float dv = dis[node];
    float4 bb = ((const float4*)b2v)[j];
    float4 r = make_float4(fmaf(dv, aA.x, bb.x), fmaf(dv, aA.y, bb.y),
                           fmaf(dv, aA.z, bb.z), fmaf(dv, aA.w, bb.w));
    r.x = fmaxf(r.x, 0.f); r.y = fmaxf(r.y, 0.f);
    r.z = fmaxf(r.z, 0.f); r.w = fmaxf(r.w, 0.f);
    // mm3: dot(h2, W3), quad j partial -> 4-lane reduce
    float4 w3 = ((const float4*)W3)[j];
    float pd = r.x * w3.x + r.y * w3.y + r.z * w3.z + r.w * w3.w;
    pd += __shfl_xor(pd, 1, 4);
    pd += __shfl_xor(pd, 2, 4);
    if (j == 0) hws3[node] = pd * dv;           // temporal: re-read randomly by k_g1
}

// Layer-3 gather, 1 channel from the 800KB pre-scaled table (L2-resident).
// 4 lanes/node, uint4 csr chunks (NT), 2-step shuffle reduce.
__global__ __launch_bounds__(256) void k_g1(
    const int2* __restrict__ odn, const unsigned* __restrict__ csr,
    const float* __restrict__ dis, const float* __restrict__ hws3,
    const float* __restrict__ b, float* __restrict__ out) {
    int t = threadIdx.x;
    int node = blockIdx.x * 64 + (t >> 2);
    int j = t & 3;
    int2 od = odn[node];
    int s0 = od.x, dg = od.y;
    float a0 = 0.f, a1 = 0.f;
    for (int c0 = 4 * j; c0 + 4 <= dg; c0 += 16) {
        u32x4 e = nt_load4(csr + s0 + c0);
        a0 += hws3[e.x];
        a1 += hws3[e.y];
        a0 += hws3[e.z];
        a1 += hws3[e.w];
    }
    if ((dg & 3) && j == ((dg >> 2) & 3)) {     // scalar tail, owner lane
        for (int k2 = dg & ~3; k2 < dg; ++k2)
            a0 += hws3[__builtin_nontemporal_load(csr + s0 + k2)];
    }
    float acc = a0 + a1;
    acc += __shfl_xor(acc, 1, 4);
    acc += __shfl_xor(acc, 2, 4);
    if (j == 0)
        __builtin_nontemporal_store(fmaf(dis[node], acc + hws3[node], b[0]),
                                    out + node);
}

extern "C" void kernel_launch(void* const* d_in, const int* in_sizes, int n_in,
                              void* d_out, int out_size, void* d_ws, size_t ws_size,
                              hipStream_t stream) {
    const float* x  = (const float*)d_in[0];
    const int*   ew = (const int*)d_in[1];
    const float* W1 = (const float*)d_in[2];
    const float* b1 = (const float*)d_in[3];
    const float* W2 = (const float*)d_in[4];
    const float* b2 = (const float*)d_in[5];
    const float* W3 = (const float*)d_in[6];
    const float* b3 = (const float*)d_in[7];
    float* out = (float*)d_out;

    // Workspace (4-byte words), ~90 MB.
    unsigned* stage = (unsigned*)d_ws;               // NCB*CAP = 7,225,344
    unsigned* csr   = stage + (long)NCB * CAP;       // 7,225,344
    int*      gcur  = (int*)(csr + (long)NCB * CAP); // 256
    int*      flag  = gcur + 256;                    // 16
    int2*     odn   = (int2*)(flag + 16);            // 200,704 int2
    float*    dis   = (float*)(odn + 200704);        // 200,704
    float4*   bufA  = (float4*)(dis + 200704);       // 4*200,064 float4 (hws1 / hws3)
    float4*   bufB  = bufA + 4 * 200064;             // 4*200,064 float4 (hws2)

    const int n = NN;
    const long e = EE;
    int nb = (n + 255) / 256;   // 782
    int gb = n / 64;            // 3125, exact

    k_detect<<<1, 256, 0, stream>>>(ew, flag, gcur);
    // partition -> counting sort (metadata) -> layer-1 matmul (dis-scaled)
    k_passA<<<NTILE, 256, 0, stream>>>(ew, flag, gcur, stage, e);
    k_sortB<<<NCB, 1024, 0, stream>>>(stage, gcur, dis, odn, csr, n);
    k_mm1<<<nb, 256, 0, stream>>>(x, W1, dis, bufA, n);
    // layer-1 aggregate + relu + mm2 (fused) -> hws2
    k_g16a<<<gb, 256, 0, stream>>>(odn, csr, dis, bufA, b1, W2, bufB);
    // layer-2 aggregate + relu + mm3 (fused) -> hws3
    k_g16b<<<gb, 256, 0, stream>>>(odn, csr, dis, bufB, b2, W3, (float*)bufA);
    // layer-3 aggregate -> out
    k_g1<<<gb, 256, 0, stream>>>(odn, csr, dis, (const float*)bufA, b3, out);
}

// Round 22
// 421.837 us; speedup vs baseline: 2.0680x; 2.0680x over previous
//
#include <hip/hip_runtime.h>

#define NN 200000
#define EE 6400000L
#define NCB 196          // coarse buckets of 1024 nodes
#define CAP 36864        // fixed bucket capacity; mean 32653 + 6σ + pad < CAP
#define TILE 4096        // LDS 22.7KB -> 7 blocks/CU for passA
#define NTILE 1563       // ceil(6400000/4096)

typedef unsigned u32x4 __attribute__((ext_vector_type(4)));

__device__ inline void f4add(float4& a, const float4 v) {
    a.x += v.x; a.y += v.y; a.z += v.z; a.w += v.w;
}

// NT load of 4 csr entries — sequential read-once stream; NT keeps it from
// evicting the randomly-gathered tab rows out of L2. (NT on scattered STORES
// is catastrophic — round 21: 8x write amplification. Loads only.)
__device__ inline u32x4 nt_load4(const unsigned* p) {
    return __builtin_nontemporal_load((const u32x4*)p);
}

// ---------------------------------------------------------------------------
// Edge-index dtype hedge (int64 vs int32): if int64 with values < 2^31, every
// odd 32-bit word is zero. flag=1 -> int64 (word idx = elem<<1), 0 -> int32.
// Also initializes the per-bucket segment cursors gcur[b] = b*CAP.
// ---------------------------------------------------------------------------
__global__ void k_detect(const int* __restrict__ w, int* __restrict__ flag,
                         int* __restrict__ gcur) {
    __shared__ int any;
    if (threadIdx.x == 0) any = 0;
    __syncthreads();
    int found = 0;
    for (int i = threadIdx.x; i < 8192; i += 256)
        if (w[2 * i + 1] != 0) found = 1;
    if (found) atomicOr(&any, 1);
    if (threadIdx.x < NCB) gcur[threadIdx.x] = threadIdx.x * CAP;
    __syncthreads();
    if (threadIdx.x == 0) flag[0] = any ? 0 : 1;
}

// Partition into coarse buckets with tile-exclusive segments (fixed capacity).
// stage entry: src[17:0] | local_dst[27:18]. All accesses TEMPORAL (scattered
// stores need L2 write-coalescing).
__global__ __launch_bounds__(256) void k_passA(
    const int* __restrict__ ew, const int* __restrict__ flag,
    int* __restrict__ gcur, unsigned* __restrict__ stage, long e) {
    __shared__ unsigned lv[TILE];
    __shared__ unsigned char lb[TILE];
    __shared__ int lh[NCB], lseg[NCB], lcur[NCB];
    for (int i = threadIdx.x; i < NCB; i += 256) { lh[i] = 0; lcur[i] = 0; }
    __syncthreads();
    long t0 = (long)blockIdx.x * TILE;
    int cnt = (int)min((long)TILE, e - t0);
    int shift = *flag;
    for (int i = threadIdx.x; i < cnt; i += 256) {
        int s = ew[(t0 + i) << shift];
        int d = ew[(EE + t0 + i) << shift];
        int b = d >> 10;
        lv[i] = (unsigned)s | ((unsigned)(d & 1023) << 18);
        lb[i] = (unsigned char)b;
        atomicAdd(&lh[b], 1);
    }
    __syncthreads();
    for (int i = threadIdx.x; i < NCB; i += 256)
        if (lh[i]) lseg[i] = atomicAdd(&gcur[i], lh[i]);
    __syncthreads();
    for (int i = threadIdx.x; i < cnt; i += 256) {
        int b = lb[i];
        int r = atomicAdd(&lcur[b], 1);
        stage[lseg[b] + r] = lv[i];
    }
}

// Per-bucket counting sort: stage (bucket-grouped) -> csr (node-grouped, src).
// Node segments padded to 4-entry (16B) alignment for uint4 csr loads.
// Emits odn = {offset, degree} and dis. All accesses TEMPORAL.
__global__ __launch_bounds__(1024) void k_sortB(
    const unsigned* __restrict__ stage, const int* __restrict__ gcur,
    float* __restrict__ dis, int2* __restrict__ odn,
    unsigned* __restrict__ csr, int n) {
    __shared__ int cnt[1024];
    __shared__ int cur[1024];
    __shared__ int wsum[16];
    int t = threadIdx.x, B = blockIdx.x;
    cnt[t] = 0;
    __syncthreads();
    int s0 = B * CAP, s1 = gcur[B];
    for (int i = s0 + t; i < s1; i += 1024)
        atomicAdd(&cnt[stage[i] >> 18], 1);
    __syncthreads();
    int c = cnt[t];
    int pc = (c + 3) & ~3;              // pad to 4 entries (16B) for uint4 loads
    int lane = t & 63, w = t >> 6;
    int s = pc;
#pragma unroll
    for (int o = 1; o < 64; o <<= 1) {
        int u = __shfl_up(s, o, 64);
        if (lane >= o) s += u;
    }
    if (lane == 63) wsum[w] = s;
    __syncthreads();
    int add = 0;
    for (int k = 0; k < w; ++k) add += wsum[k];
    int excl = s - pc + add;
    cur[t] = excl;
    int node = B * 1024 + t;
    if (node < n) {
        odn[node] = make_int2(s0 + excl, c);
        dis[node] = rsqrtf((float)(c + 1));
    }
    __syncthreads();
    for (int i = s0 + t; i < s1; i += 1024) {
        unsigned v = stage[i];
        int pos = s0 + atomicAdd(&cur[v >> 18], 1);
        csr[pos] = v & 0x3FFFF;
    }
}

// Layer 1 matmul: hws = dis ⊙ (x @ W1), row-major float4 quads.
__global__ __launch_bounds__(256) void k_mm1(
    const float* __restrict__ x, const float* __restrict__ W,
    const float* __restrict__ dis, float4* __restrict__ outr, int n) {
    __shared__ float Wl[256 * 16];
    int t = threadIdx.x;
#pragma unroll
    for (int i = 0; i < 4; ++i)
        ((float4*)Wl)[t + i * 256] = ((const float4*)W)[t + i * 256];
    __syncthreads();

    int node = blockIdx.x * 256 + t;
    if (node >= n) return;

    const float4* xr = (const float4*)(x + (long)node * 256);
    float acc[16];
#pragma unroll
    for (int o = 0; o < 16; ++o) acc[o] = 0.f;

#pragma unroll 8
    for (int kk = 0; kk < 64; ++kk) {
        float4 xv = xr[kk];
#pragma unroll
        for (int q = 0; q < 4; ++q) {
            float xs = (q == 0) ? xv.x : (q == 1) ? xv.y : (q == 2) ? xv.z : xv.w;
            const float4* wr = (const float4*)&Wl[(kk * 4 + q) * 16];
#pragma unroll
            for (int oo = 0; oo < 4; ++oo) {
                float4 wv = wr[oo];
                acc[oo * 4 + 0] = fmaf(xs, wv.x, acc[oo * 4 + 0]);
                acc[oo * 4 + 1] = fmaf(xs, wv.y, acc[oo * 4 + 1]);
                acc[oo * 4 + 2] = fmaf(xs, wv.z, acc[oo * 4 + 2]);
                acc[oo * 4 + 3] = fmaf(xs, wv.w, acc[oo * 4 + 3]);
            }
        }
    }
    float dv = dis[node];
#pragma unroll
    for (int q = 0; q < 4; ++q)
        outr[node * 4 + q] = make_float4(acc[q * 4] * dv, acc[q * 4 + 1] * dv,
                                         acc[q * 4 + 2] * dv, acc[q * 4 + 3] * dv);
}

// Shared gather core: quad-chunk unroll — 4 lane-uniform uint4 csr loads (NT
// reads: keep the read-once csr stream from evicting tab rows) and 16
// independent 16B gathers (temporal) in flight per lane.
__device__ inline float4 gather_quad(const unsigned* __restrict__ csr, int s0,
                                     int dg, const float4* __restrict__ tab,
                                     int j) {
    float4 a0 = make_float4(0.f, 0.f, 0.f, 0.f);
    float4 a1 = make_float4(0.f, 0.f, 0.f, 0.f);
    float4 a2 = make_float4(0.f, 0.f, 0.f, 0.f);
    float4 a3 = make_float4(0.f, 0.f, 0.f, 0.f);
    int k = 0;
    for (; k + 16 <= dg; k += 16) {
        u32x4 e0 = nt_load4(csr + s0 + k);
        u32x4 e1 = nt_load4(csr + s0 + k + 4);
        u32x4 e2 = nt_load4(csr + s0 + k + 8);
        u32x4 e3 = nt_load4(csr + s0 + k + 12);
        f4add(a0, tab[e0.x * 4 + j]); f4add(a1, tab[e1.x * 4 + j]);
        f4add(a2, tab[e2.x * 4 + j]); f4add(a3, tab[e3.x * 4 + j]);
        f4add(a0, tab[e0.y * 4 + j]); f4add(a1, tab[e1.y * 4 + j]);
        f4add(a2, tab[e2.y * 4 + j]); f4add(a3, tab[e3.y * 4 + j]);
        f4add(a0, tab[e0.z * 4 + j]); f4add(a1, tab[e1.z * 4 + j]);
        f4add(a2, tab[e2.z * 4 + j]); f4add(a3, tab[e3.z * 4 + j]);
        f4add(a0, tab[e0.w * 4 + j]); f4add(a1, tab[e1.w * 4 + j]);
        f4add(a2, tab[e2.w * 4 + j]); f4add(a3, tab[e3.w * 4 + j]);
    }
    if (k + 8 <= dg) {
        u32x4 eL = nt_load4(csr + s0 + k);
        u32x4 eH = nt_load4(csr + s0 + k + 4);
        f4add(a0, tab[eL.x * 4 + j]); f4add(a1, tab[eH.x * 4 + j]);
        f4add(a0, tab[eL.y * 4 + j]); f4add(a1, tab[eH.y * 4 + j]);
        f4add(a0, tab[eL.z * 4 + j]); f4add(a1, tab[eH.z * 4 + j]);
        f4add(a0, tab[eL.w * 4 + j]); f4add(a1, tab[eH.w * 4 + j]);
        k += 8;
    }
    if (k + 4 <= dg) {
        u32x4 e = nt_load4(csr + s0 + k);
        f4add(a0, tab[e.x * 4 + j]);
        f4add(a1, tab[e.y * 4 + j]);
        f4add(a2, tab[e.z * 4 + j]);
        f4add(a3, tab[e.w * 4 + j]);
        k += 4;
    }
    for (; k < dg; ++k)
        f4add(a0, tab[csr[s0 + k] * 4 + j]);
    f4add(a0, a1); f4add(a2, a3); f4add(a0, a2);
    return a0;
}

// Layer-1 gather + relu + FUSED mm2 + scale. 4 lanes/node, 64 nodes/block
// (grid exactly n/64 -> barrier-safe). Epilogue: h1 quad -> LDS (stride 17),
// barrier, each lane computes quad j of dis*(h1@W2).
__global__ __launch_bounds__(256) void k_g16a(
    const int2* __restrict__ odn, const unsigned* __restrict__ csr,
    const float* __restrict__ dis, const float4* __restrict__ tab,
    const float* __restrict__ b1v, const float* __restrict__ W2,
    float4* __restrict__ out2) {
    __shared__ float h1s[64 * 17];
    __shared__ float W2l[256];
    int t = threadIdx.x;
    if (t < 64) ((float4*)W2l)[t] = ((const float4*)W2)[t];
    int node = blockIdx.x * 64 + (t >> 2);
    int j = t & 3;
    int2 od = odn[node];
    float4 aA = gather_quad(csr, od.x, od.y, tab, j);
    f4add(aA, tab[node * 4 + j]);               // self-loop (pre-scaled)
    float dv = dis[node];
    float4 bb = ((const float4*)b1v)[j];
    float4 r = make_float4(fmaf(dv, aA.x, bb.x), fmaf(dv, aA.y, bb.y),
                           fmaf(dv, aA.z, bb.z), fmaf(dv, aA.w, bb.w));
    r.x = fmaxf(r.x, 0.f); r.y = fmaxf(r.y, 0.f);
    r.z = fmaxf(r.z, 0.f); r.w = fmaxf(r.w, 0.f);
    int nl = t >> 2;
    h1s[nl * 17 + 4 * j + 0] = r.x;
    h1s[nl * 17 + 4 * j + 1] = r.y;
    h1s[nl * 17 + 4 * j + 2] = r.z;
    h1s[nl * 17 + 4 * j + 3] = r.w;
    __syncthreads();
    // mm2: quad j of dis * (h1 @ W2)
    float4 acc = make_float4(0.f, 0.f, 0.f, 0.f);
#pragma unroll
    for (int kk = 0; kk < 16; ++kk) {
        float hv = h1s[nl * 17 + kk];
        float4 wv = ((const float4*)&W2l[kk * 16])[j];
        acc.x = fmaf(hv, wv.x, acc.x);
        acc.y = fmaf(hv, wv.y, acc.y);
        acc.z = fmaf(hv, wv.z, acc.z);
        acc.w = fmaf(hv, wv.w, acc.w);
    }
    out2[(long)node * 4 + j] = make_float4(acc.x * dv, acc.y * dv,
                                           acc.z * dv, acc.w * dv);
}

// Layer-2 gather + relu + FUSED mm3 + scale: writes hws3 (1 float/node).
__global__ __launch_bounds__(256) void k_g16b(
    const int2* __restrict__ odn, const unsigned* __restrict__ csr,
    const float* __restrict__ dis, const float4* __restrict__ tab,
    const float* __restrict__ b2v, const float* __restrict__ W3,
    float* __restrict__ hws3) {
    int t = threadIdx.x;
    int node = blockIdx.x * 64 + (t >> 2);
    int j = t & 3;
    int2 od = odn[node];
    float4 aA = gather_quad(csr, od.x, od.y, tab, j);
    f4add(aA, tab[node * 4 + j]);               // self-loop (pre-scaled)
    float dv = dis[node];
    float4 bb = ((const float4*)b2v)[j];
    float4 r = make_float4(fmaf(dv, aA.x, bb.x), fmaf(dv, aA.y, bb.y),
                           fmaf(dv, aA.z, bb.z), fmaf(dv, aA.w, bb.w));
    r.x = fmaxf(r.x, 0.f); r.y = fmaxf(r.y, 0.f);
    r.z = fmaxf(r.z, 0.f); r.w = fmaxf(r.w, 0.f);
    // mm3: dot(h2, W3), quad j partial -> 4-lane reduce
    float4 w3 = ((const float4*)W3)[j];
    float pd = r.x * w3.x + r.y * w3.y + r.z * w3.z + r.w * w3.w;
    pd += __shfl_xor(pd, 1, 4);
    pd += __shfl_xor(pd, 2, 4);
    if (j == 0) hws3[node] = pd * dv;
}

// Layer-3 gather, 1 channel from the 800KB pre-scaled table (L2-resident).
// 4 lanes/node, uint4 csr chunks (NT reads), 2-step shuffle reduce.
__global__ __launch_bounds__(256) void k_g1(
    const int2* __restrict__ odn, const unsigned* __restrict__ csr,
    const float* __restrict__ dis, const float* __restrict__ hws3,
    const float* __restrict__ b, float* __restrict__ out) {
    int t = threadIdx.x;
    int node = blockIdx.x * 64 + (t >> 2);
    int j = t & 3;
    int2 od = odn[node];
    int s0 = od.x, dg = od.y;
    float a0 = 0.f, a1 = 0.f;
    for (int c0 = 4 * j; c0 + 4 <= dg; c0 += 16) {
        u32x4 e = nt_load4(csr + s0 + c0);
        a0 += hws3[e.x];
        a1 += hws3[e.y];
        a0 += hws3[e.z];
        a1 += hws3[e.w];
    }
    if ((dg & 3) && j == ((dg >> 2) & 3)) {     // scalar tail, owner lane
        for (int k2 = dg & ~3; k2 < dg; ++k2)
            a0 += hws3[csr[s0 + k2]];
    }
    float acc = a0 + a1;
    acc += __shfl_xor(acc, 1, 4);
    acc += __shfl_xor(acc, 2, 4);
    if (j == 0)
        out[node] = fmaf(dis[node], acc + hws3[node], b[0]);
}

extern "C" void kernel_launch(void* const* d_in, const int* in_sizes, int n_in,
                              void* d_out, int out_size, void* d_ws, size_t ws_size,
                              hipStream_t stream) {
    const float* x  = (const float*)d_in[0];
    const int*   ew = (const int*)d_in[1];
    const float* W1 = (const float*)d_in[2];
    const float* b1 = (const float*)d_in[3];
    const float* W2 = (const float*)d_in[4];
    const float* b2 = (const float*)d_in[5];
    const float* W3 = (const float*)d_in[6];
    const float* b3 = (const float*)d_in[7];
    float* out = (float*)d_out;

    // Workspace (4-byte words), ~90 MB.
    unsigned* stage = (unsigned*)d_ws;               // NCB*CAP = 7,225,344
    unsigned* csr   = stage + (long)NCB * CAP;       // 7,225,344
    int*      gcur  = (int*)(csr + (long)NCB * CAP); // 256
    int*      flag  = gcur + 256;                    // 16
    int2*     odn   = (int2*)(flag + 16);            // 200,704 int2
    float*    dis   = (float*)(odn + 200704);        // 200,704
    float4*   bufA  = (float4*)(dis + 200704);       // 4*200,064 float4 (hws1 / hws3)
    float4*   bufB  = bufA + 4 * 200064;             // 4*200,064 float4 (hws2)

    const int n = NN;
    const long e = EE;
    int nb = (n + 255) / 256;   // 782
    int gb = n / 64;            // 3125, exact

    k_detect<<<1, 256, 0, stream>>>(ew, flag, gcur);
    // partition -> counting sort (metadata) -> layer-1 matmul (dis-scaled)
    k_passA<<<NTILE, 256, 0, stream>>>(ew, flag, gcur, stage, e);
    k_sortB<<<NCB, 1024, 0, stream>>>(stage, gcur, dis, odn, csr, n);
    k_mm1<<<nb, 256, 0, stream>>>(x, W1, dis, bufA, n);
    // layer-1 aggregate + relu + mm2 (fused) -> hws2
    k_g16a<<<gb, 256, 0, stream>>>(odn, csr, dis, bufA, b1, W2, bufB);
    // layer-2 aggregate + relu + mm3 (fused) -> hws3
    k_g16b<<<gb, 256, 0, stream>>>(odn, csr, dis, bufB, b2, W3, (float*)bufA);
    // layer-3 aggregate -> out
    k_g1<<<gb, 256, 0, stream>>>(odn, csr, dis, (const float*)bufA, b3, out);
}

// Round 23
// 407.492 us; speedup vs baseline: 2.1408x; 1.0352x over previous
//
#include <hip/hip_runtime.h>

#define NN 200000
#define EE 6400000L
#define NCB 196          // coarse buckets of 1024 nodes
#define CAP 36864        // fixed bucket capacity; mean 32653 + 6σ + pad < CAP
#define TILE 4096        // LDS 22.7KB -> 7 blocks/CU for passA
#define NTILE 1563       // ceil(6400000/4096)

__device__ inline void f4add(float4& a, const float4 v) {
    a.x += v.x; a.y += v.y; a.z += v.z; a.w += v.w;
}

// ---------------------------------------------------------------------------
// Edge-index dtype hedge (int64 vs int32): if int64 with values < 2^31, every
// odd 32-bit word is zero. flag=1 -> int64 (word idx = elem<<1), 0 -> int32.
// Also initializes the per-bucket segment cursors gcur[b] = b*CAP.
// ---------------------------------------------------------------------------
__global__ void k_detect(const int* __restrict__ w, int* __restrict__ flag,
                         int* __restrict__ gcur) {
    __shared__ int any;
    if (threadIdx.x == 0) any = 0;
    __syncthreads();
    int found = 0;
    for (int i = threadIdx.x; i < 8192; i += 256)
        if (w[2 * i + 1] != 0) found = 1;
    if (found) atomicOr(&any, 1);
    if (threadIdx.x < NCB) gcur[threadIdx.x] = threadIdx.x * CAP;
    __syncthreads();
    if (threadIdx.x == 0) flag[0] = any ? 0 : 1;
}

// Partition into coarse buckets with tile-exclusive segments (fixed capacity).
// stage entry: src[17:0] | local_dst[27:18]
__global__ __launch_bounds__(256) void k_passA(
    const int* __restrict__ ew, const int* __restrict__ flag,
    int* __restrict__ gcur, unsigned* __restrict__ stage, long e) {
    __shared__ unsigned lv[TILE];
    __shared__ unsigned char lb[TILE];
    __shared__ int lh[NCB], lseg[NCB], lcur[NCB];
    for (int i = threadIdx.x; i < NCB; i += 256) { lh[i] = 0; lcur[i] = 0; }
    __syncthreads();
    long t0 = (long)blockIdx.x * TILE;
    int cnt = (int)min((long)TILE, e - t0);
    int shift = *flag;
    for (int i = threadIdx.x; i < cnt; i += 256) {
        int s = ew[(t0 + i) << shift];
        int d = ew[(EE + t0 + i) << shift];
        int b = d >> 10;
        lv[i] = (unsigned)s | ((unsigned)(d & 1023) << 18);
        lb[i] = (unsigned char)b;
        atomicAdd(&lh[b], 1);
    }
    __syncthreads();
    for (int i = threadIdx.x; i < NCB; i += 256)
        if (lh[i]) lseg[i] = atomicAdd(&gcur[i], lh[i]);
    __syncthreads();
    for (int i = threadIdx.x; i < cnt; i += 256) {
        int b = lb[i];
        int r = atomicAdd(&lcur[b], 1);
        stage[lseg[b] + r] = lv[i];
    }
}

// Per-bucket counting sort: stage (bucket-grouped) -> csr (node-grouped, src).
// Node segments padded to 4-entry (16B) alignment for uint4 csr loads.
// Emits odn = {offset, degree} and dis.
__global__ __launch_bounds__(1024) void k_sortB(
    const unsigned* __restrict__ stage, const int* __restrict__ gcur,
    float* __restrict__ dis, int2* __restrict__ odn,
    unsigned* __restrict__ csr, int n) {
    __shared__ int cnt[1024];
    __shared__ int cur[1024];
    __shared__ int wsum[16];
    int t = threadIdx.x, B = blockIdx.x;
    cnt[t] = 0;
    __syncthreads();
    int s0 = B * CAP, s1 = gcur[B];
    for (int i = s0 + t; i < s1; i += 1024)
        atomicAdd(&cnt[stage[i] >> 18], 1);
    __syncthreads();
    int c = cnt[t];
    int pc = (c + 3) & ~3;              // pad to 4 entries (16B) for uint4 loads
    int lane = t & 63, w = t >> 6;
    int s = pc;
#pragma unroll
    for (int o = 1; o < 64; o <<= 1) {
        int u = __shfl_up(s, o, 64);
        if (lane >= o) s += u;
    }
    if (lane == 63) wsum[w] = s;
    __syncthreads();
    int add = 0;
    for (int k = 0; k < w; ++k) add += wsum[k];
    int excl = s - pc + add;
    cur[t] = excl;
    int node = B * 1024 + t;
    if (node < n) {
        odn[node] = make_int2(s0 + excl, c);
        dis[node] = rsqrtf((float)(c + 1));
    }
    __syncthreads();
    for (int i = s0 + t; i < s1; i += 1024) {
        unsigned v = stage[i];
        int pos = s0 + atomicAdd(&cur[v >> 18], 1);
        csr[pos] = v & 0x3FFFF;
    }
}

// Layer 1 matmul: hws = dis ⊙ (x @ W1), row-major float4 quads.
__global__ __launch_bounds__(256) void k_mm1(
    const float* __restrict__ x, const float* __restrict__ W,
    const float* __restrict__ dis, float4* __restrict__ outr, int n) {
    __shared__ float Wl[256 * 16];
    int t = threadIdx.x;
#pragma unroll
    for (int i = 0; i < 4; ++i)
        ((float4*)Wl)[t + i * 256] = ((const float4*)W)[t + i * 256];
    __syncthreads();

    int node = blockIdx.x * 256 + t;
    if (node >= n) return;

    const float4* xr = (const float4*)(x + (long)node * 256);
    float acc[16];
#pragma unroll
    for (int o = 0; o < 16; ++o) acc[o] = 0.f;

#pragma unroll 8
    for (int kk = 0; kk < 64; ++kk) {
        float4 xv = xr[kk];
#pragma unroll
        for (int q = 0; q < 4; ++q) {
            float xs = (q == 0) ? xv.x : (q == 1) ? xv.y : (q == 2) ? xv.z : xv.w;
            const float4* wr = (const float4*)&Wl[(kk * 4 + q) * 16];
#pragma unroll
            for (int oo = 0; oo < 4; ++oo) {
                float4 wv = wr[oo];
                acc[oo * 4 + 0] = fmaf(xs, wv.x, acc[oo * 4 + 0]);
                acc[oo * 4 + 1] = fmaf(xs, wv.y, acc[oo * 4 + 1]);
                acc[oo * 4 + 2] = fmaf(xs, wv.z, acc[oo * 4 + 2]);
                acc[oo * 4 + 3] = fmaf(xs, wv.w, acc[oo * 4 + 3]);
            }
        }
    }
    float dv = dis[node];
#pragma unroll
    for (int q = 0; q < 4; ++q)
        outr[node * 4 + q] = make_float4(acc[q * 4] * dv, acc[q * 4 + 1] * dv,
                                         acc[q * 4 + 2] * dv, acc[q * 4 + 3] * dv);
}

// Shared gather core: quad-chunk unroll — 4 lane-uniform uint4 csr loads and
// 16 independent 16B gathers in flight per lane. Returns the summed quad.
__device__ inline float4 gather_quad(const unsigned* __restrict__ csr, int s0,
                                     int dg, const float4* __restrict__ tab,
                                     int j) {
    float4 a0 = make_float4(0.f, 0.f, 0.f, 0.f);
    float4 a1 = make_float4(0.f, 0.f, 0.f, 0.f);
    float4 a2 = make_float4(0.f, 0.f, 0.f, 0.f);
    float4 a3 = make_float4(0.f, 0.f, 0.f, 0.f);
    int k = 0;
    for (; k + 16 <= dg; k += 16) {
        uint4 e0 = *(const uint4*)(csr + s0 + k);
        uint4 e1 = *(const uint4*)(csr + s0 + k + 4);
        uint4 e2 = *(const uint4*)(csr + s0 + k + 8);
        uint4 e3 = *(const uint4*)(csr + s0 + k + 12);
        f4add(a0, tab[e0.x * 4 + j]); f4add(a1, tab[e1.x * 4 + j]);
        f4add(a2, tab[e2.x * 4 + j]); f4add(a3, tab[e3.x * 4 + j]);
        f4add(a0, tab[e0.y * 4 + j]); f4add(a1, tab[e1.y * 4 + j]);
        f4add(a2, tab[e2.y * 4 + j]); f4add(a3, tab[e3.y * 4 + j]);
        f4add(a0, tab[e0.z * 4 + j]); f4add(a1, tab[e1.z * 4 + j]);
        f4add(a2, tab[e2.z * 4 + j]); f4add(a3, tab[e3.z * 4 + j]);
        f4add(a0, tab[e0.w * 4 + j]); f4add(a1, tab[e1.w * 4 + j]);
        f4add(a2, tab[e2.w * 4 + j]); f4add(a3, tab[e3.w * 4 + j]);
    }
    if (k + 8 <= dg) {
        uint4 eL = *(const uint4*)(csr + s0 + k);
        uint4 eH = *(const uint4*)(csr + s0 + k + 4);
        f4add(a0, tab[eL.x * 4 + j]); f4add(a1, tab[eH.x * 4 + j]);
        f4add(a0, tab[eL.y * 4 + j]); f4add(a1, tab[eH.y * 4 + j]);
        f4add(a0, tab[eL.z * 4 + j]); f4add(a1, tab[eH.z * 4 + j]);
        f4add(a0, tab[eL.w * 4 + j]); f4add(a1, tab[eH.w * 4 + j]);
        k += 8;
    }
    if (k + 4 <= dg) {
        uint4 e = *(const uint4*)(csr + s0 + k);
        f4add(a0, tab[e.x * 4 + j]);
        f4add(a1, tab[e.y * 4 + j]);
        f4add(a2, tab[e.z * 4 + j]);
        f4add(a3, tab[e.w * 4 + j]);
        k += 4;
    }
    for (; k < dg; ++k)
        f4add(a0, tab[csr[s0 + k] * 4 + j]);
    f4add(a0, a1); f4add(a2, a3); f4add(a0, a2);
    return a0;
}

// Layer-1 gather + relu + FUSED mm2 + scale. 4 lanes/node, 64 nodes/block
// (grid exactly n/64 -> barrier-safe). Epilogue: h1 quad -> LDS (stride 17),
// barrier, each lane computes quad j of dis*(h1@W2).
__global__ __launch_bounds__(256) void k_g16a(
    const int2* __restrict__ odn, const unsigned* __restrict__ csr,
    const float* __restrict__ dis, const float4* __restrict__ tab,
    const float* __restrict__ b1v, const float* __restrict__ W2,
    float4* __restrict__ out2) {
    __shared__ float h1s[64 * 17];
    __shared__ float W2l[256];
    int t = threadIdx.x;
    if (t < 64) ((float4*)W2l)[t] = ((const float4*)W2)[t];
    int node = blockIdx.x * 64 + (t >> 2);
    int j = t & 3;
    int2 od = odn[node];
    float4 aA = gather_quad(csr, od.x, od.y, tab, j);
    f4add(aA, tab[node * 4 + j]);               // self-loop (pre-scaled)
    float dv = dis[node];
    float4 bb = ((const float4*)b1v)[j];
    float4 r = make_float4(fmaf(dv, aA.x, bb.x), fmaf(dv, aA.y, bb.y),
                           fmaf(dv, aA.z, bb.z), fmaf(dv, aA.w, bb.w));
    r.x = fmaxf(r.x, 0.f); r.y = fmaxf(r.y, 0.f);
    r.z = fmaxf(r.z, 0.f); r.w = fmaxf(r.w, 0.f);
    int nl = t >> 2;
    h1s[nl * 17 + 4 * j + 0] = r.x;
    h1s[nl * 17 + 4 * j + 1] = r.y;
    h1s[nl * 17 + 4 * j + 2] = r.z;
    h1s[nl * 17 + 4 * j + 3] = r.w;
    __syncthreads();
    // mm2: quad j of dis * (h1 @ W2)
    float4 acc = make_float4(0.f, 0.f, 0.f, 0.f);
#pragma unroll
    for (int kk = 0; kk < 16; ++kk) {
        float hv = h1s[nl * 17 + kk];
        float4 wv = ((const float4*)&W2l[kk * 16])[j];
        acc.x = fmaf(hv, wv.x, acc.x);
        acc.y = fmaf(hv, wv.y, acc.y);
        acc.z = fmaf(hv, wv.z, acc.z);
        acc.w = fmaf(hv, wv.w, acc.w);
    }
    out2[(long)node * 4 + j] = make_float4(acc.x * dv, acc.y * dv,
                                           acc.z * dv, acc.w * dv);
}

// Layer-2 gather + relu + FUSED mm3 + scale: writes hws3 (1 float/node).
__global__ __launch_bounds__(256) void k_g16b(
    const int2* __restrict__ odn, const unsigned* __restrict__ csr,
    const float* __restrict__ dis, const float4* __restrict__ tab,
    const float* __restrict__ b2v, const float* __restrict__ W3,
    float* __restrict__ hws3) {
    int t = threadIdx.x;
    int node = blockIdx.x * 64 + (t >> 2);
    int j = t & 3;
    int2 od = odn[node];
    float4 aA = gather_quad(csr, od.x, od.y, tab, j);
    f4add(aA, tab[node * 4 + j]);               // self-loop (pre-scaled)
    float dv = dis[node];
    float4 bb = ((const float4*)b2v)[j];
    float4 r = make_float4(fmaf(dv, aA.x, bb.x), fmaf(dv, aA.y, bb.y),
                           fmaf(dv, aA.z, bb.z), fmaf(dv, aA.w, bb.w));
    r.x = fmaxf(r.x, 0.f); r.y = fmaxf(r.y, 0.f);
    r.z = fmaxf(r.z, 0.f); r.w = fmaxf(r.w, 0.f);
    // mm3: dot(h2, W3), quad j partial -> 4-lane reduce
    float4 w3 = ((const float4*)W3)[j];
    float pd = r.x * w3.x + r.y * w3.y + r.z * w3.z + r.w * w3.w;
    pd += __shfl_xor(pd, 1, 4);
    pd += __shfl_xor(pd, 2, 4);
    if (j == 0) hws3[node] = pd * dv;
}

// Layer-3 gather, 1 channel from the 800KB pre-scaled table (L2-resident).
// 4 lanes/node, uint4 csr chunks, 2-step shuffle reduce.
__global__ __launch_bounds__(256) void k_g1(
    const int2* __restrict__ odn, const unsigned* __restrict__ csr,
    const float* __restrict__ dis, const float* __restrict__ hws3,
    const float* __restrict__ b, float* __restrict__ out) {
    int t = threadIdx.x;
    int node = blockIdx.x * 64 + (t >> 2);
    int j = t & 3;
    int2 od = odn[node];
    int s0 = od.x, dg = od.y;
    float a0 = 0.f, a1 = 0.f;
    for (int c0 = 4 * j; c0 + 4 <= dg; c0 += 16) {
        uint4 e = *(const uint4*)(csr + s0 + c0);
        a0 += hws3[e.x];
        a1 += hws3[e.y];
        a0 += hws3[e.z];
        a1 += hws3[e.w];
    }
    if ((dg & 3) && j == ((dg >> 2) & 3)) {     // scalar tail, owner lane
        for (int k2 = dg & ~3; k2 < dg; ++k2)
            a0 += hws3[csr[s0 + k2]];
    }
    float acc = a0 + a1;
    acc += __shfl_xor(acc, 1, 4);
    acc += __shfl_xor(acc, 2, 4);
    if (j == 0)
        out[node] = fmaf(dis[node], acc + hws3[node], b[0]);
}

extern "C" void kernel_launch(void* const* d_in, const int* in_sizes, int n_in,
                              void* d_out, int out_size, void* d_ws, size_t ws_size,
                              hipStream_t stream) {
    const float* x  = (const float*)d_in[0];
    const int*   ew = (const int*)d_in[1];
    const float* W1 = (const float*)d_in[2];
    const float* b1 = (const float*)d_in[3];
    const float* W2 = (const float*)d_in[4];
    const float* b2 = (const float*)d_in[5];
    const float* W3 = (const float*)d_in[6];
    const float* b3 = (const float*)d_in[7];
    float* out = (float*)d_out;

    // Workspace (4-byte words), ~90 MB.
    unsigned* stage = (unsigned*)d_ws;               // NCB*CAP = 7,225,344
    unsigned* csr   = stage + (long)NCB * CAP;       // 7,225,344
    int*      gcur  = (int*)(csr + (long)NCB * CAP); // 256
    int*      flag  = gcur + 256;                    // 16
    int2*     odn   = (int2*)(flag + 16);            // 200,704 int2
    float*    dis   = (float*)(odn + 200704);        // 200,704
    float4*   bufA  = (float4*)(dis + 200704);       // 4*200,064 float4 (hws1 / hws3)
    float4*   bufB  = bufA + 4 * 200064;             // 4*200,064 float4 (hws2)

    const int n = NN;
    const long e = EE;
    int nb = (n + 255) / 256;   // 782
    int gb = n / 64;            // 3125, exact

    k_detect<<<1, 256, 0, stream>>>(ew, flag, gcur);
    // partition -> counting sort (metadata) -> layer-1 matmul (dis-scaled)
    k_passA<<<NTILE, 256, 0, stream>>>(ew, flag, gcur, stage, e);
    k_sortB<<<NCB, 1024, 0, stream>>>(stage, gcur, dis, odn, csr, n);
    k_mm1<<<nb, 256, 0, stream>>>(x, W1, dis, bufA, n);
    // layer-1 aggregate + relu + mm2 (fused) -> hws2
    k_g16a<<<gb, 256, 0, stream>>>(odn, csr, dis, bufA, b1, W2, bufB);
    // layer-2 aggregate + relu + mm3 (fused) -> hws3
    k_g16b<<<gb, 256, 0, stream>>>(odn, csr, dis, bufB, b2, W3, (float*)bufA);
    // layer-3 aggregate -> out
    k_g1<<<gb, 256, 0, stream>>>(odn, csr, dis, (const float*)bufA, b3, out);
}